// Round 14
// baseline (288.931 us; speedup 1.0000x reference)
//
#include <hip/hip_runtime.h>

#define TT 6
#define D 128
#define BM 64
#define CAP 1152          // LDS sort capacity per 64-row bucket (mean ~767, +14 sigma)
#define SUBCAP 256        // slots per (bucket, shard); mean ~96, +16 sigma
#define LN_EPS 1e-5f

typedef __bf16 bf16x8 __attribute__((ext_vector_type(8)));
typedef float f32x4 __attribute__((ext_vector_type(4)));

__device__ __forceinline__ unsigned short f2bf(float f) {
    unsigned int u = __float_as_uint(f);
    unsigned int r = (u + 0x7FFFu + ((u >> 16) & 1u)) >> 16;  // RNE
    return (unsigned short)r;
}
__device__ __forceinline__ float bflo(unsigned int v) { return __uint_as_float(v << 16); }
__device__ __forceinline__ float bfhi(unsigned int v) { return __uint_as_float(v & 0xffff0000u); }

// XOR-swizzled LDS offset (ushort elems) for 128-elem rows: 16 chunks of 8.
__device__ __forceinline__ int lds_off128(int row, int kgrp) {
    return row * 128 + (((kgrp & 7) ^ (row & 7)) | (kgrp & 8)) * 8;
}

// --- single regular kernel (2 graph nodes total: memset + this):
//     A: block-range-specialized prep with batched (MLP-friendly) bodies
//     -- capacity-guaranteed grid barrier (22KB LDS -> 7 blk/CU -> 1792 slots
//        >= 782 blocks; r13-proven fences; relaxed-load spin, no RMW storm)
//     B: r11 fused path (verbatim)
__launch_bounds__(256, 3)
__global__ void mega_kernel(const float* __restrict__ x, const float* __restrict__ W_l,
                            const float* __restrict__ W_r, const float* __restrict__ b,
                            const float* __restrict__ emb,
                            const int* __restrict__ ei, const int* __restrict__ et,
                            unsigned short* __restrict__ xb, unsigned short* __restrict__ WlT,
                            float* __restrict__ bias_total, int* __restrict__ bcursor,
                            int* __restrict__ gctr, int* __restrict__ ebuf,
                            const float* __restrict__ gamma, const float* __restrict__ beta,
                            float* __restrict__ out,
                            int total8, int E, int N) {
    __shared__ unsigned short As[BM * 128];     // 16 KB swizzled; rows wave-private
    __shared__ int bcnt[TT * BM];               // per-(t,row) counts
    __shared__ int bcur[TT * BM];               // scatter cursors -> segment ends
    __shared__ unsigned short esrt[CAP];        // locally sorted src indices

    int tid = threadIdx.x;
    int bid = blockIdx.x;
    int NBK = gridDim.x;

    // ---- A: block-range-specialized prep
    int XB_BLKS = (total8 + 2047) / 2048;            // x-cast blocks (8 items/thread)
    int W_BLKS  = (7 * 2048 + 255) / 256;            // weight-transpose blocks
    int EDGE0   = XB_BLKS + W_BLKS + 1;              // first edge block

    if (bid < XB_BLKS) {
        // x-cast: 8 items/thread in 2 batches of 4 (independent loads -> MLP)
        int base = bid * 2048 + tid;
#pragma unroll
        for (int h = 0; h < 2; ++h) {
            float4 a[4], c[4];
            int idx[4];
#pragma unroll
            for (int k = 0; k < 4; ++k) {
                idx[k] = base + (h * 4 + k) * 256;
                if (idx[k] < total8) {
                    const float4* p = (const float4*)x + (size_t)idx[k] * 2;
                    a[k] = p[0]; c[k] = p[1];
                }
            }
#pragma unroll
            for (int k = 0; k < 4; ++k) {
                if (idx[k] < total8) {
                    uint4 o;
                    o.x = (unsigned int)f2bf(a[k].x) | ((unsigned int)f2bf(a[k].y) << 16);
                    o.y = (unsigned int)f2bf(a[k].z) | ((unsigned int)f2bf(a[k].w) << 16);
                    o.z = (unsigned int)f2bf(c[k].x) | ((unsigned int)f2bf(c[k].y) << 16);
                    o.w = (unsigned int)f2bf(c[k].z) | ((unsigned int)f2bf(c[k].w) << 16);
                    ((uint4*)xb)[idx[k]] = o;
                }
            }
        }
    } else if (bid < XB_BLKS + W_BLKS) {
        // weight transpose: j = (s*16+kg)*128+n -> frag write at ushort off j*8
        int j = (bid - XB_BLKS) * 256 + tid;
        if (j < 7 * 2048) {
            int s = j >> 11, rem = j & 2047, kg = rem >> 7, n = rem & 127;
            float w[8];
            if (s < TT) {
#pragma unroll
                for (int k = 0; k < 8; ++k)
                    w[k] = W_l[s * D * D + (kg * 8 + k) * D + n];
            } else {
#pragma unroll
                for (int k = 0; k < 8; ++k) {
                    float sum = 0.f;
#pragma unroll
                    for (int t = 0; t < TT; ++t)
                        sum += W_r[t * D * D + (kg * 8 + k) * D + n];
                    w[k] = sum;
                }
            }
            uint4 o;
            o.x = (unsigned int)f2bf(w[0]) | ((unsigned int)f2bf(w[1]) << 16);
            o.y = (unsigned int)f2bf(w[2]) | ((unsigned int)f2bf(w[3]) << 16);
            o.z = (unsigned int)f2bf(w[4]) | ((unsigned int)f2bf(w[5]) << 16);
            o.w = (unsigned int)f2bf(w[6]) | ((unsigned int)f2bf(w[7]) << 16);
            *(uint4*)&WlT[(size_t)j * 8] = o;
        }
    } else if (bid == XB_BLKS + W_BLKS) {
        if (tid < D) {
            float s = 0.f;
#pragma unroll
            for (int t = 0; t < TT; ++t) s += b[t * D + tid] + emb[t * D + tid];
            bias_total[tid] = s;
        }
    } else {
        // edge fill: batch-8 loads, then 8 independent atomics+stores
        int shard = bid & 7;
        int estride = (NBK - EDGE0) * 2048;
#pragma unroll 1
        for (int e0 = (bid - EDGE0) * 2048; e0 < E; e0 += estride) {
            int es[8], ed[8], ety[8];
#pragma unroll
            for (int k = 0; k < 8; ++k) {
                int e = e0 + k * 256 + tid;
                es[k] = (e < E) ? ei[e] : -1;
                ed[k] = (e < E) ? ei[E + e] : 0;
                ety[k] = (e < E) ? et[e] : 0;
            }
#pragma unroll
            for (int k = 0; k < 8; ++k) {
                if (es[k] >= 0) {
                    int bkt = ed[k] >> 6;
                    int pos = atomicAdd(&bcursor[(shard * NBK + bkt) * 16], 1);
                    if (pos < SUBCAP)
                        ebuf[(size_t)bkt * (8 * SUBCAP) + shard * SUBCAP + pos] =
                            (es[k] << 9) | ((ed[k] & 63) << 3) | ety[k];
                }
            }
        }
    }

    // ---- grid barrier (deadlock-free: all blocks co-resident by capacity)
    __syncthreads();                 // all waves' stores drained (vmcnt 0 @ barrier)
    if (tid == 0) {
        __threadfence();             // release: L2 writeback to device scope
        atomicAdd(gctr, 1);
        while (__hip_atomic_load(gctr, __ATOMIC_RELAXED, __HIP_MEMORY_SCOPE_AGENT)
               < (int)gridDim.x) {
            __builtin_amdgcn_s_sleep(32);
        }
        __threadfence();             // acquire: invalidate stale L1/L2 lines
    }
    __syncthreads();

    // ---- B: fused path (r11 verbatim)
    int lane = tid & 63, wave = tid >> 6;
    int q = lane >> 4, c16 = lane & 15;
    int qid = tid >> 4, l16 = tid & 15;         // 16 groups x 16 lanes
    int blockRow = bid * BM;

    // phase 0: load this bucket's packed edges (8 shards, 1 slot/thread each)
    size_t base = (size_t)bid * (8 * SUBCAP);
#pragma unroll
    for (int j = 0; j < 2; ++j) {
        int idx = tid + j * 256;
        if (idx < TT * BM) { bcnt[idx] = 0; }
    }
    int pk[8];
#pragma unroll
    for (int j = 0; j < 8; ++j) {
        int bcj = bcursor[(j * NBK + bid) * 16];
        if (bcj > SUBCAP) bcj = SUBCAP;
        pk[j] = (tid < bcj) ? ebuf[base + j * SUBCAP + tid] : -1;
    }
    __syncthreads();   // bcnt zeros visible
#pragma unroll
    for (int j = 0; j < 8; ++j)
        if (pk[j] >= 0) atomicAdd(&bcnt[(pk[j] & 7) * 64 + ((pk[j] >> 3) & 63)], 1);
    __syncthreads();

    // phase 1: wave 0 scans the 384 counters (6 per lane)
    if (wave == 0) {
        int c[6];
        int ts = 0;
#pragma unroll
        for (int j = 0; j < 6; ++j) { c[j] = bcnt[lane * 6 + j]; ts += c[j]; }
        int inc = ts;
#pragma unroll
        for (int o = 1; o < 64; o <<= 1) {
            int n = __shfl_up(inc, o);
            if (lane >= o) inc += n;
        }
        int run = inc - ts;
#pragma unroll
        for (int j = 0; j < 6; ++j) { bcur[lane * 6 + j] = run; run += c[j]; }
    }
    __syncthreads();

    // phase 2: scatter src into locally-sorted order
#pragma unroll
    for (int j = 0; j < 8; ++j)
        if (pk[j] >= 0) {
            int s = (pk[j] & 7) * 64 + ((pk[j] >> 3) & 63);
            int p = atomicAdd(&bcur[s], 1);
            if (p < CAP) esrt[p] = (unsigned short)(pk[j] >> 9);
        }
    __syncthreads();   // sort complete; bcnt/bcur/esrt read-only from here

    f32x4 acc[8];
#pragma unroll
    for (int ct = 0; ct < 8; ++ct) acc[ct] = (f32x4){0.f, 0.f, 0.f, 0.f};

    // per-lane B fragment base: frag (t,kgrp,ct) at ((t*16+kgrp)*128 + ct*16+c16)*8
    const unsigned short* Bbase = WlT + ((size_t)q * 128 + c16) * 8;

#pragma unroll 1
    for (int t = 0; t < 7; ++t) {
        bf16x8 afx[4];
        if (t < TT) {
            // gather: 16-lane group handles 4 rows in 2 pairs, prefetch-4 + tail
#pragma unroll
            for (int pr = 0; pr < 2; ++pr) {
                int e0[2], cn[2];
#pragma unroll
                for (int i = 0; i < 2; ++i) {
                    int row = qid * 4 + pr * 2 + i;
                    int s = t * 64 + row;
                    int c = bcnt[s];
                    cn[i] = c;
                    e0[i] = bcur[s] - c;   // bcur = segment end after scatter
                }
                int ix[2][4];
#pragma unroll
                for (int i = 0; i < 2; ++i)
#pragma unroll
                    for (int j = 0; j < 4; ++j)
                        ix[i][j] = (cn[i] > j) ? (int)esrt[e0[i] + j] : 0;
                uint4 v[2][4];
#pragma unroll
                for (int i = 0; i < 2; ++i)
#pragma unroll
                    for (int j = 0; j < 4; ++j) {
                        v[i][j] = (uint4){0u, 0u, 0u, 0u};
                        if (cn[i] > j)
                            v[i][j] = *(const uint4*)(xb + (size_t)ix[i][j] * D + l16 * 8);
                    }
#pragma unroll
                for (int i = 0; i < 2; ++i) {
                    float a0 = bflo(v[i][0].x) + bflo(v[i][1].x) + bflo(v[i][2].x) + bflo(v[i][3].x);
                    float a1 = bfhi(v[i][0].x) + bfhi(v[i][1].x) + bfhi(v[i][2].x) + bfhi(v[i][3].x);
                    float a2 = bflo(v[i][0].y) + bflo(v[i][1].y) + bflo(v[i][2].y) + bflo(v[i][3].y);
                    float a3 = bfhi(v[i][0].y) + bfhi(v[i][1].y) + bfhi(v[i][2].y) + bfhi(v[i][3].y);
                    float a4 = bflo(v[i][0].z) + bflo(v[i][1].z) + bflo(v[i][2].z) + bflo(v[i][3].z);
                    float a5 = bfhi(v[i][0].z) + bfhi(v[i][1].z) + bfhi(v[i][2].z) + bfhi(v[i][3].z);
                    float a6 = bflo(v[i][0].w) + bflo(v[i][1].w) + bflo(v[i][2].w) + bflo(v[i][3].w);
                    float a7 = bfhi(v[i][0].w) + bfhi(v[i][1].w) + bfhi(v[i][2].w) + bfhi(v[i][3].w);
                    int e = e0[i] + 4, end = e0[i] + cn[i];
#pragma unroll 1
                    while (e < end) {
                        int s = (int)esrt[e++];
                        uint4 vv = *(const uint4*)(xb + (size_t)s * D + l16 * 8);
                        a0 += bflo(vv.x); a1 += bfhi(vv.x);
                        a2 += bflo(vv.y); a3 += bfhi(vv.y);
                        a4 += bflo(vv.z); a5 += bfhi(vv.z);
                        a6 += bflo(vv.w); a7 += bfhi(vv.w);
                    }
                    if (cn[i] > 1) {
                        float sc = 1.f / (float)cn[i];
                        a0 *= sc; a1 *= sc; a2 *= sc; a3 *= sc;
                        a4 *= sc; a5 *= sc; a6 *= sc; a7 *= sc;
                    }
                    uint4 p;
                    p.x = (unsigned int)f2bf(a0) | ((unsigned int)f2bf(a1) << 16);
                    p.y = (unsigned int)f2bf(a2) | ((unsigned int)f2bf(a3) << 16);
                    p.z = (unsigned int)f2bf(a4) | ((unsigned int)f2bf(a5) << 16);
                    p.w = (unsigned int)f2bf(a6) | ((unsigned int)f2bf(a7) << 16);
                    *(uint4*)&As[lds_off128(qid * 4 + pr * 2 + i, l16)] = p;
                }
            }
        } else {
            // x-slab: A-fragments straight from global xb (no staging)
            int gr = blockRow + wave * 16 + c16; if (gr >= N) gr = N - 1;
#pragma unroll
            for (int ks = 0; ks < 4; ++ks)
                afx[ks] = *(const bf16x8*)(xb + (size_t)gr * D + (ks * 4 + q) * 8);
        }

        // MFMA: K=128 in 4 steps; A from wave-private LDS (or regs), B from L2
        const unsigned short* Bt = Bbase + (size_t)t * 16384;
#pragma unroll
        for (int ks = 0; ks < 4; ++ks) {
            bf16x8 af;
            if (t < TT)
                af = *(const bf16x8*)&As[lds_off128(wave * 16 + c16, ks * 4 + q)];
            else
                af = afx[ks];
#pragma unroll
            for (int ct = 0; ct < 8; ++ct) {
                bf16x8 bfr = *(const bf16x8*)(Bt + ks * 4096 + ct * 128);
                acc[ct] = __builtin_amdgcn_mfma_f32_16x16x32_bf16(af, bfr, acc[ct], 0, 0, 0);
            }
        }
        // no barrier: As rows written and read only by this wave
    }

    // epilogue: bias + LayerNorm + ReLU (fully in-wave, 16-lane row groups)
    float bias_c[8], g_c[8], bt_c[8];
#pragma unroll
    for (int ct = 0; ct < 8; ++ct) {
        int col = ct * 16 + c16;
        bias_c[ct] = bias_total[col];
        g_c[ct] = gamma[col];
        bt_c[ct] = beta[col];
    }
#pragma unroll
    for (int reg = 0; reg < 4; ++reg) {
        float h[8];
        float s = 0.f, s2 = 0.f;
#pragma unroll
        for (int ct = 0; ct < 8; ++ct) {
            h[ct] = acc[ct][reg] + bias_c[ct];
            s += h[ct];
            s2 += h[ct] * h[ct];
        }
#pragma unroll
        for (int o = 8; o >= 1; o >>= 1) {
            s  += __shfl_xor(s, o, 16);
            s2 += __shfl_xor(s2, o, 16);
        }
        float mu = s * (1.f / 128.f);
        float var = s2 * (1.f / 128.f) - mu * mu;
        float rstd = rsqrtf(var + LN_EPS);
        int row = blockRow + wave * 16 + q * 4 + reg;
        if (row < N) {
#pragma unroll
            for (int ct = 0; ct < 8; ++ct) {
                float y = (h[ct] - mu) * rstd * g_c[ct] + bt_c[ct];
                out[(size_t)row * D + ct * 16 + c16] = fmaxf(y, 0.f);
            }
        }
    }
}

extern "C" void kernel_launch(void* const* d_in, const int* in_sizes, int n_in,
                              void* d_out, int out_size, void* d_ws, size_t ws_size,
                              hipStream_t stream) {
    const float* x     = (const float*)d_in[0];
    const int*   ei    = (const int*)d_in[1];
    const int*   et    = (const int*)d_in[2];
    const float* W_l   = (const float*)d_in[3];
    const float* W_r   = (const float*)d_in[4];
    const float* b     = (const float*)d_in[5];
    const float* emb   = (const float*)d_in[6];
    const float* gamma = (const float*)d_in[7];
    const float* beta  = (const float*)d_in[8];

    int N = in_sizes[0] / D;
    int E = in_sizes[2];
    int NBLK = (N + BM - 1) / BM;      // also the bucket count (dst>>6)

    // workspace carve
    int* bcursor = (int*)d_ws;                            // 8*NBLK*16 (line-padded)
    int* gctr    = bcursor + 8 * NBLK * 16;               // 16 (barrier counter)
    int* ebuf    = gctr + 16;                             // NBLK * 8*SUBCAP slots
    size_t ofs = (size_t)((char*)(ebuf + (size_t)NBLK * 8 * SUBCAP) - (char*)d_ws);
    ofs = (ofs + 15) & ~(size_t)15;
    unsigned short* WlT = (unsigned short*)((char*)d_ws + ofs);   // 7*16*128*8 ushort
    float* bias_total = (float*)(WlT + 7 * 2048 * 8);             // 128
    size_t ofs2 = (size_t)((char*)(bias_total + D) - (char*)d_ws);
    ofs2 = (ofs2 + 15) & ~(size_t)15;
    unsigned short* xb = (unsigned short*)((char*)d_ws + ofs2);   // N*128 bf16

    // one memset node: shard cursors + barrier counter
    hipMemsetAsync(bcursor, 0, (size_t)(8 * NBLK * 16 + 16) * sizeof(int), stream);

    int total8 = N * D / 8;
    mega_kernel<<<NBLK, 256, 0, stream>>>(x, W_l, W_r, b, emb, ei, et,
                                          xb, WlT, bias_total, bcursor, gctr, ebuf,
                                          gamma, beta, (float*)d_out,
                                          total8, E, N);
}

// Round 16
// 182.344 us; speedup vs baseline: 1.5845x; 1.5845x over previous
//
#include <hip/hip_runtime.h>

#define TT 6
#define D 128
#define BM 64
#define CAP 1152          // LDS sort capacity per 64-row bucket (mean ~767, +14 sigma)
#define SUBCAP 256        // slots per (bucket, shard); mean ~96, +16 sigma
#define LN_EPS 1e-5f

typedef __bf16 bf16x8 __attribute__((ext_vector_type(8)));
typedef float f32x4 __attribute__((ext_vector_type(4)));
typedef float fvec4 __attribute__((ext_vector_type(4)));   // native vec for NT builtins

__device__ __forceinline__ unsigned short f2bf(float f) {
    unsigned int u = __float_as_uint(f);
    unsigned int r = (u + 0x7FFFu + ((u >> 16) & 1u)) >> 16;  // RNE
    return (unsigned short)r;
}
__device__ __forceinline__ float bflo(unsigned int v) { return __uint_as_float(v << 16); }
__device__ __forceinline__ float bfhi(unsigned int v) { return __uint_as_float(v & 0xffff0000u); }

// XOR-swizzled LDS offset (ushort elems) for 128-elem rows: 16 chunks of 8.
__device__ __forceinline__ int lds_off128(int row, int kgrp) {
    return row * 128 + (((kgrp & 7) ^ (row & 7)) | (kgrp & 8)) * 8;
}

// --- prep: x-cast (NT loads: x read once), weight transpose, bias_total,
//     AND XCD-sharded bucket fill. All parts data-independent, barrier-free.
//     (cursors pre-zeroed by the memset node.) ---
__global__ void prep_kernel(const float* __restrict__ x, const float* __restrict__ W_l,
                            const float* __restrict__ W_r, const float* __restrict__ b,
                            const float* __restrict__ emb,
                            const int* __restrict__ ei, const int* __restrict__ et,
                            unsigned short* __restrict__ xb, unsigned short* __restrict__ WlT,
                            float* __restrict__ bias_total, int* __restrict__ bcursor,
                            int* __restrict__ ebuf,
                            int total8, int E, int N, int NBK) {
    int i = blockIdx.x * 256 + threadIdx.x;
    if (i < total8) {
        const fvec4* p = (const fvec4*)x + (size_t)i * 2;
        fvec4 a = __builtin_nontemporal_load(p);         // x read exactly once
        fvec4 bb = __builtin_nontemporal_load(p + 1);
        uint4 o;
        o.x = (unsigned int)f2bf(a.x) | ((unsigned int)f2bf(a.y) << 16);
        o.y = (unsigned int)f2bf(a.z) | ((unsigned int)f2bf(a.w) << 16);
        o.z = (unsigned int)f2bf(bb.x) | ((unsigned int)f2bf(bb.y) << 16);
        o.w = (unsigned int)f2bf(bb.z) | ((unsigned int)f2bf(bb.w) << 16);
        ((uint4*)xb)[i] = o;                             // xb re-read by fused: keep cached
        return;
    }
    i -= total8;
    if (i < 7 * 2048) {
        // i = (s*16 + kg)*128 + n  ->  WlT2 frag write at ushort offset i*8 (coalesced)
        int s = i >> 11, rem = i & 2047, kg = rem >> 7, n = rem & 127;
        float w[8];
        if (s < TT) {
#pragma unroll
            for (int j = 0; j < 8; ++j)
                w[j] = W_l[s * D * D + (kg * 8 + j) * D + n];
        } else {
#pragma unroll
            for (int j = 0; j < 8; ++j) {
                float sum = 0.f;
#pragma unroll
                for (int t = 0; t < TT; ++t)
                    sum += W_r[t * D * D + (kg * 8 + j) * D + n];
                w[j] = sum;
            }
        }
        uint4 o;
        o.x = (unsigned int)f2bf(w[0]) | ((unsigned int)f2bf(w[1]) << 16);
        o.y = (unsigned int)f2bf(w[2]) | ((unsigned int)f2bf(w[3]) << 16);
        o.z = (unsigned int)f2bf(w[4]) | ((unsigned int)f2bf(w[5]) << 16);
        o.w = (unsigned int)f2bf(w[6]) | ((unsigned int)f2bf(w[7]) << 16);
        *(uint4*)&WlT[(size_t)i * 8] = o;
        return;
    }
    i -= 7 * 2048;
    if (i < D) {
        float s = 0.f;
#pragma unroll
        for (int t = 0; t < TT; ++t) s += b[t * D + i] + emb[t * D + i];
        bias_total[i] = s;
        return;
    }
    i -= D;
    if (i < E) {
        int src = ei[i], dst = ei[E + i], t = et[i];
        int bkt = dst >> 6;
        int shard = blockIdx.x & 7;
        int pos = atomicAdd(&bcursor[(shard * NBK + bkt) * 16], 1);
        if (pos < SUBCAP)
            ebuf[(size_t)bkt * (8 * SUBCAP) + shard * SUBCAP + pos] =
                (src << 9) | ((dst & 63) << 3) | t;
    }
}

// --- fused: 8-shard coalesced bucket load -> LDS counting sort (int ds atomics)
//     -> barrier-free gather/MFMA (wave-private As, B streamed L2->reg)
//     -> bias+LN+ReLU with nontemporal out stores (kill RFO). ---
__launch_bounds__(256, 3)
__global__ void fused_kernel(const unsigned short* __restrict__ xb,
                             const int* __restrict__ bcursor, const int* __restrict__ ebuf,
                             const unsigned short* __restrict__ WlT,
                             const float* __restrict__ bias_total,
                             const float* __restrict__ gamma, const float* __restrict__ beta,
                             float* __restrict__ out, int N) {
    __shared__ unsigned short As[BM * 128];     // 16 KB swizzled; rows wave-private
    __shared__ int bcnt[TT * BM];               // per-(t,row) counts
    __shared__ int bcur[TT * BM];               // scatter cursors -> segment ends
    __shared__ unsigned short esrt[CAP];        // locally sorted src indices

    int tid = threadIdx.x;
    int lane = tid & 63, wave = tid >> 6;
    int q = lane >> 4, c16 = lane & 15;
    int qid = tid >> 4, l16 = tid & 15;         // 16 groups x 16 lanes
    int blockRow = blockIdx.x * BM;
    int NBK = gridDim.x;

    // phase 0: load this bucket's packed edges (8 shards, 1 slot/thread each)
    size_t base = (size_t)blockIdx.x * (8 * SUBCAP);
#pragma unroll
    for (int j = 0; j < 2; ++j) {
        int idx = tid + j * 256;
        if (idx < TT * BM) { bcnt[idx] = 0; }
    }
    int pk[8];
#pragma unroll
    for (int j = 0; j < 8; ++j) {
        int bcj = bcursor[(j * NBK + blockIdx.x) * 16];
        if (bcj > SUBCAP) bcj = SUBCAP;
        pk[j] = (tid < bcj) ? ebuf[base + j * SUBCAP + tid] : -1;
    }
    __syncthreads();   // bcnt zeros visible
#pragma unroll
    for (int j = 0; j < 8; ++j)
        if (pk[j] >= 0) atomicAdd(&bcnt[(pk[j] & 7) * 64 + ((pk[j] >> 3) & 63)], 1);
    __syncthreads();

    // phase 1: wave 0 scans the 384 counters (6 per lane)
    if (wave == 0) {
        int c[6];
        int ts = 0;
#pragma unroll
        for (int j = 0; j < 6; ++j) { c[j] = bcnt[lane * 6 + j]; ts += c[j]; }
        int inc = ts;
#pragma unroll
        for (int o = 1; o < 64; o <<= 1) {
            int n = __shfl_up(inc, o);
            if (lane >= o) inc += n;
        }
        int run = inc - ts;
#pragma unroll
        for (int j = 0; j < 6; ++j) { bcur[lane * 6 + j] = run; run += c[j]; }
    }
    __syncthreads();

    // phase 2: scatter src into locally-sorted order
#pragma unroll
    for (int j = 0; j < 8; ++j)
        if (pk[j] >= 0) {
            int s = (pk[j] & 7) * 64 + ((pk[j] >> 3) & 63);
            int p = atomicAdd(&bcur[s], 1);
            if (p < CAP) esrt[p] = (unsigned short)(pk[j] >> 9);
        }
    __syncthreads();   // sort complete; bcnt/bcur/esrt read-only from here

    f32x4 acc[8];
#pragma unroll
    for (int ct = 0; ct < 8; ++ct) acc[ct] = (f32x4){0.f, 0.f, 0.f, 0.f};

    // per-lane B fragment base: frag (t,kgrp,ct) at ((t*16+kgrp)*128 + ct*16+c16)*8
    const unsigned short* Bbase = WlT + ((size_t)q * 128 + c16) * 8;

#pragma unroll 1
    for (int t = 0; t < 7; ++t) {
        bf16x8 afx[4];
        if (t < TT) {
            // gather: 16-lane group handles 4 rows in 2 pairs, prefetch-4 + tail
#pragma unroll
            for (int pr = 0; pr < 2; ++pr) {
                int e0[2], cn[2];
#pragma unroll
                for (int i = 0; i < 2; ++i) {
                    int row = qid * 4 + pr * 2 + i;
                    int s = t * 64 + row;
                    int c = bcnt[s];
                    cn[i] = c;
                    e0[i] = bcur[s] - c;   // bcur = segment end after scatter
                }
                int ix[2][4];
#pragma unroll
                for (int i = 0; i < 2; ++i)
#pragma unroll
                    for (int j = 0; j < 4; ++j)
                        ix[i][j] = (cn[i] > j) ? (int)esrt[e0[i] + j] : 0;
                uint4 v[2][4];
#pragma unroll
                for (int i = 0; i < 2; ++i)
#pragma unroll
                    for (int j = 0; j < 4; ++j) {
                        v[i][j] = (uint4){0u, 0u, 0u, 0u};
                        if (cn[i] > j)
                            v[i][j] = *(const uint4*)(xb + (size_t)ix[i][j] * D + l16 * 8);
                    }
#pragma unroll
                for (int i = 0; i < 2; ++i) {
                    float a0 = bflo(v[i][0].x) + bflo(v[i][1].x) + bflo(v[i][2].x) + bflo(v[i][3].x);
                    float a1 = bfhi(v[i][0].x) + bfhi(v[i][1].x) + bfhi(v[i][2].x) + bfhi(v[i][3].x);
                    float a2 = bflo(v[i][0].y) + bflo(v[i][1].y) + bflo(v[i][2].y) + bflo(v[i][3].y);
                    float a3 = bfhi(v[i][0].y) + bfhi(v[i][1].y) + bfhi(v[i][2].y) + bfhi(v[i][3].y);
                    float a4 = bflo(v[i][0].z) + bflo(v[i][1].z) + bflo(v[i][2].z) + bflo(v[i][3].z);
                    float a5 = bfhi(v[i][0].z) + bfhi(v[i][1].z) + bfhi(v[i][2].z) + bfhi(v[i][3].z);
                    float a6 = bflo(v[i][0].w) + bflo(v[i][1].w) + bflo(v[i][2].w) + bflo(v[i][3].w);
                    float a7 = bfhi(v[i][0].w) + bfhi(v[i][1].w) + bfhi(v[i][2].w) + bfhi(v[i][3].w);
                    int e = e0[i] + 4, end = e0[i] + cn[i];
#pragma unroll 1
                    while (e < end) {
                        int s = (int)esrt[e++];
                        uint4 vv = *(const uint4*)(xb + (size_t)s * D + l16 * 8);
                        a0 += bflo(vv.x); a1 += bfhi(vv.x);
                        a2 += bflo(vv.y); a3 += bfhi(vv.y);
                        a4 += bflo(vv.z); a5 += bfhi(vv.z);
                        a6 += bflo(vv.w); a7 += bfhi(vv.w);
                    }
                    if (cn[i] > 1) {
                        float sc = 1.f / (float)cn[i];
                        a0 *= sc; a1 *= sc; a2 *= sc; a3 *= sc;
                        a4 *= sc; a5 *= sc; a6 *= sc; a7 *= sc;
                    }
                    uint4 p;
                    p.x = (unsigned int)f2bf(a0) | ((unsigned int)f2bf(a1) << 16);
                    p.y = (unsigned int)f2bf(a2) | ((unsigned int)f2bf(a3) << 16);
                    p.z = (unsigned int)f2bf(a4) | ((unsigned int)f2bf(a5) << 16);
                    p.w = (unsigned int)f2bf(a6) | ((unsigned int)f2bf(a7) << 16);
                    *(uint4*)&As[lds_off128(qid * 4 + pr * 2 + i, l16)] = p;
                }
            }
        } else {
            // x-slab: A-fragments straight from global xb (no staging)
            int gr = blockRow + wave * 16 + c16; if (gr >= N) gr = N - 1;
#pragma unroll
            for (int ks = 0; ks < 4; ++ks)
                afx[ks] = *(const bf16x8*)(xb + (size_t)gr * D + (ks * 4 + q) * 8);
        }

        // MFMA: K=128 in 4 steps; A from wave-private LDS (or regs), B from L2
        const unsigned short* Bt = Bbase + (size_t)t * 16384;
#pragma unroll
        for (int ks = 0; ks < 4; ++ks) {
            bf16x8 af;
            if (t < TT)
                af = *(const bf16x8*)&As[lds_off128(wave * 16 + c16, ks * 4 + q)];
            else
                af = afx[ks];
#pragma unroll
            for (int ct = 0; ct < 8; ++ct) {
                bf16x8 bfr = *(const bf16x8*)(Bt + ks * 4096 + ct * 128);
                acc[ct] = __builtin_amdgcn_mfma_f32_16x16x32_bf16(af, bfr, acc[ct], 0, 0, 0);
            }
        }
        // no barrier: As rows written and read only by this wave
    }

    // epilogue: bias + LayerNorm + ReLU; nontemporal stores (out never re-read)
    float bias_c[8], g_c[8], bt_c[8];
#pragma unroll
    for (int ct = 0; ct < 8; ++ct) {
        int col = ct * 16 + c16;
        bias_c[ct] = bias_total[col];
        g_c[ct] = gamma[col];
        bt_c[ct] = beta[col];
    }
#pragma unroll
    for (int reg = 0; reg < 4; ++reg) {
        float h[8];
        float s = 0.f, s2 = 0.f;
#pragma unroll
        for (int ct = 0; ct < 8; ++ct) {
            h[ct] = acc[ct][reg] + bias_c[ct];
            s += h[ct];
            s2 += h[ct] * h[ct];
        }
#pragma unroll
        for (int o = 8; o >= 1; o >>= 1) {
            s  += __shfl_xor(s, o, 16);
            s2 += __shfl_xor(s2, o, 16);
        }
        float mu = s * (1.f / 128.f);
        float var = s2 * (1.f / 128.f) - mu * mu;
        float rstd = rsqrtf(var + LN_EPS);
        int row = blockRow + wave * 16 + q * 4 + reg;
        if (row < N) {
#pragma unroll
            for (int ct = 0; ct < 8; ++ct) {
                float y = (h[ct] - mu) * rstd * g_c[ct] + bt_c[ct];
                __builtin_nontemporal_store(fmaxf(y, 0.f),
                    out + (size_t)row * D + ct * 16 + c16);
            }
        }
    }
}

extern "C" void kernel_launch(void* const* d_in, const int* in_sizes, int n_in,
                              void* d_out, int out_size, void* d_ws, size_t ws_size,
                              hipStream_t stream) {
    const float* x     = (const float*)d_in[0];
    const int*   ei    = (const int*)d_in[1];
    const int*   et    = (const int*)d_in[2];
    const float* W_l   = (const float*)d_in[3];
    const float* W_r   = (const float*)d_in[4];
    const float* b     = (const float*)d_in[5];
    const float* emb   = (const float*)d_in[6];
    const float* gamma = (const float*)d_in[7];
    const float* beta  = (const float*)d_in[8];

    int N = in_sizes[0] / D;
    int E = in_sizes[2];
    int NBLK = (N + BM - 1) / BM;      // also the bucket count (dst>>6)

    // workspace carve
    int* bcursor = (int*)d_ws;                            // 8*NBLK*16 (line-padded)
    int* ebuf    = bcursor + 8 * NBLK * 16;               // NBLK * 8*SUBCAP slots
    size_t ofs = (size_t)((char*)(ebuf + (size_t)NBLK * 8 * SUBCAP) - (char*)d_ws);
    ofs = (ofs + 15) & ~(size_t)15;
    unsigned short* WlT = (unsigned short*)((char*)d_ws + ofs);   // 7*16*128*8 ushort
    float* bias_total = (float*)(WlT + 7 * 2048 * 8);             // 128
    size_t ofs2 = (size_t)((char*)(bias_total + D) - (char*)d_ws);
    ofs2 = (ofs2 + 15) & ~(size_t)15;
    unsigned short* xb = (unsigned short*)((char*)d_ws + ofs2);   // N*128 bf16

    hipMemsetAsync(bcursor, 0, (size_t)(8 * NBLK * 16) * sizeof(int), stream);

    int total8 = N * D / 8;
    int G = total8 + 7 * 2048 + D + E;
    prep_kernel<<<(G + 255) / 256, 256, 0, stream>>>(x, W_l, W_r, b, emb, ei, et,
                                                     xb, WlT, bias_total, bcursor, ebuf,
                                                     total8, E, N, NBLK);

    fused_kernel<<<NBLK, 256, 0, stream>>>(xb, bcursor, ebuf, WlT, bias_total,
                                           gamma, beta, (float*)d_out, N);
}

// Round 17
// 176.830 us; speedup vs baseline: 1.6339x; 1.0312x over previous
//
#include <hip/hip_runtime.h>

#define TT 6
#define D 128
#define BM 64
#define CAP 1152          // LDS sort capacity per 64-row bucket (mean ~767, +14 sigma)
#define SUBCAP 256        // slots per (bucket, shard); mean ~96, +16 sigma
#define LN_EPS 1e-5f

typedef __bf16 bf16x8 __attribute__((ext_vector_type(8)));
typedef float f32x4 __attribute__((ext_vector_type(4)));
typedef float fvec4 __attribute__((ext_vector_type(4)));   // native vec for NT builtins

__device__ __forceinline__ unsigned short f2bf(float f) {
    unsigned int u = __float_as_uint(f);
    unsigned int r = (u + 0x7FFFu + ((u >> 16) & 1u)) >> 16;  // RNE
    return (unsigned short)r;
}
__device__ __forceinline__ float bflo(unsigned int v) { return __uint_as_float(v << 16); }
__device__ __forceinline__ float bfhi(unsigned int v) { return __uint_as_float(v & 0xffff0000u); }

// XOR-swizzled LDS offset (ushort elems) for 128-elem rows: 16 chunks of 8.
__device__ __forceinline__ int lds_off128(int row, int kgrp) {
    return row * 128 + (((kgrp & 7) ^ (row & 7)) | (kgrp & 8)) * 8;
}

// --- prep: x-cast (NT loads: x read once), weight transpose, bias_total,
//     AND XCD-sharded bucket fill. All parts data-independent, barrier-free.
//     (cursors pre-zeroed by the memset node.) ---
__global__ void prep_kernel(const float* __restrict__ x, const float* __restrict__ W_l,
                            const float* __restrict__ W_r, const float* __restrict__ b,
                            const float* __restrict__ emb,
                            const int* __restrict__ ei, const int* __restrict__ et,
                            unsigned short* __restrict__ xb, unsigned short* __restrict__ WlT,
                            float* __restrict__ bias_total, int* __restrict__ bcursor,
                            int* __restrict__ ebuf,
                            int total8, int E, int N, int NBK) {
    int i = blockIdx.x * 256 + threadIdx.x;
    if (i < total8) {
        const fvec4* p = (const fvec4*)x + (size_t)i * 2;
        fvec4 a = __builtin_nontemporal_load(p);         // x read exactly once
        fvec4 bb = __builtin_nontemporal_load(p + 1);
        uint4 o;
        o.x = (unsigned int)f2bf(a.x) | ((unsigned int)f2bf(a.y) << 16);
        o.y = (unsigned int)f2bf(a.z) | ((unsigned int)f2bf(a.w) << 16);
        o.z = (unsigned int)f2bf(bb.x) | ((unsigned int)f2bf(bb.y) << 16);
        o.w = (unsigned int)f2bf(bb.z) | ((unsigned int)f2bf(bb.w) << 16);
        ((uint4*)xb)[i] = o;                             // xb re-read by fused: keep cached
        return;
    }
    i -= total8;
    if (i < 7 * 2048) {
        // i = (s*16 + kg)*128 + n  ->  WlT2 frag write at ushort offset i*8 (coalesced)
        int s = i >> 11, rem = i & 2047, kg = rem >> 7, n = rem & 127;
        float w[8];
        if (s < TT) {
#pragma unroll
            for (int j = 0; j < 8; ++j)
                w[j] = W_l[s * D * D + (kg * 8 + j) * D + n];
        } else {
#pragma unroll
            for (int j = 0; j < 8; ++j) {
                float sum = 0.f;
#pragma unroll
                for (int t = 0; t < TT; ++t)
                    sum += W_r[t * D * D + (kg * 8 + j) * D + n];
                w[j] = sum;
            }
        }
        uint4 o;
        o.x = (unsigned int)f2bf(w[0]) | ((unsigned int)f2bf(w[1]) << 16);
        o.y = (unsigned int)f2bf(w[2]) | ((unsigned int)f2bf(w[3]) << 16);
        o.z = (unsigned int)f2bf(w[4]) | ((unsigned int)f2bf(w[5]) << 16);
        o.w = (unsigned int)f2bf(w[6]) | ((unsigned int)f2bf(w[7]) << 16);
        *(uint4*)&WlT[(size_t)i * 8] = o;
        return;
    }
    i -= 7 * 2048;
    if (i < D) {
        float s = 0.f;
#pragma unroll
        for (int t = 0; t < TT; ++t) s += b[t * D + i] + emb[t * D + i];
        bias_total[i] = s;
        return;
    }
    i -= D;
    if (i < E) {
        int src = ei[i], dst = ei[E + i], t = et[i];
        int bkt = dst >> 6;
        int shard = blockIdx.x & 7;
        int pos = atomicAdd(&bcursor[(shard * NBK + bkt) * 16], 1);
        if (pos < SUBCAP)
            ebuf[(size_t)bkt * (8 * SUBCAP) + shard * SUBCAP + pos] =
                (src << 9) | ((dst & 63) << 3) | t;
    }
}

// --- fused: 8-shard coalesced bucket load -> LDS counting sort (int ds atomics)
//     -> barrier-free gather/MFMA, t-loop FULLY UNROLLED (static indices ->
//     compiler can hoist slab t+1's row loads over slab t's reduce/MFMA)
//     -> bias+LN+ReLU with nontemporal out stores. ---
__launch_bounds__(256, 3)
__global__ void fused_kernel(const unsigned short* __restrict__ xb,
                             const int* __restrict__ bcursor, const int* __restrict__ ebuf,
                             const unsigned short* __restrict__ WlT,
                             const float* __restrict__ bias_total,
                             const float* __restrict__ gamma, const float* __restrict__ beta,
                             float* __restrict__ out, int N) {
    __shared__ unsigned short As[BM * 128];     // 16 KB swizzled; rows wave-private
    __shared__ int bcnt[TT * BM];               // per-(t,row) counts
    __shared__ int bcur[TT * BM];               // scatter cursors -> segment ends
    __shared__ unsigned short esrt[CAP];        // locally sorted src indices

    int tid = threadIdx.x;
    int lane = tid & 63, wave = tid >> 6;
    int q = lane >> 4, c16 = lane & 15;
    int qid = tid >> 4, l16 = tid & 15;         // 16 groups x 16 lanes
    int blockRow = blockIdx.x * BM;
    int NBK = gridDim.x;

    // phase 0: load this bucket's packed edges (8 shards, 1 slot/thread each)
    size_t base = (size_t)blockIdx.x * (8 * SUBCAP);
#pragma unroll
    for (int j = 0; j < 2; ++j) {
        int idx = tid + j * 256;
        if (idx < TT * BM) { bcnt[idx] = 0; }
    }
    int pk[8];
#pragma unroll
    for (int j = 0; j < 8; ++j) {
        int bcj = bcursor[(j * NBK + blockIdx.x) * 16];
        if (bcj > SUBCAP) bcj = SUBCAP;
        pk[j] = (tid < bcj) ? ebuf[base + j * SUBCAP + tid] : -1;
    }
    __syncthreads();   // bcnt zeros visible
#pragma unroll
    for (int j = 0; j < 8; ++j)
        if (pk[j] >= 0) atomicAdd(&bcnt[(pk[j] & 7) * 64 + ((pk[j] >> 3) & 63)], 1);
    __syncthreads();

    // phase 1: wave 0 scans the 384 counters (6 per lane)
    if (wave == 0) {
        int c[6];
        int ts = 0;
#pragma unroll
        for (int j = 0; j < 6; ++j) { c[j] = bcnt[lane * 6 + j]; ts += c[j]; }
        int inc = ts;
#pragma unroll
        for (int o = 1; o < 64; o <<= 1) {
            int n = __shfl_up(inc, o);
            if (lane >= o) inc += n;
        }
        int run = inc - ts;
#pragma unroll
        for (int j = 0; j < 6; ++j) { bcur[lane * 6 + j] = run; run += c[j]; }
    }
    __syncthreads();

    // phase 2: scatter src into locally-sorted order
#pragma unroll
    for (int j = 0; j < 8; ++j)
        if (pk[j] >= 0) {
            int s = (pk[j] & 7) * 64 + ((pk[j] >> 3) & 63);
            int p = atomicAdd(&bcur[s], 1);
            if (p < CAP) esrt[p] = (unsigned short)(pk[j] >> 9);
        }
    __syncthreads();   // sort complete; bcnt/bcur/esrt read-only from here

    f32x4 acc[8];
#pragma unroll
    for (int ct = 0; ct < 8; ++ct) acc[ct] = (f32x4){0.f, 0.f, 0.f, 0.f};

    // per-lane B fragment base: frag (t,kgrp,ct) at ((t*16+kgrp)*128 + ct*16+c16)*8
    const unsigned short* Bbase = WlT + ((size_t)q * 128 + c16) * 8;

    // t-loop FULLY UNROLLED: t is compile-time, all gather arrays are SSA ->
    // compiler may overlap slab t+1's independent row loads with slab t's
    // reduce + MFMA (no barriers in this loop; As rows are wave-private).
#pragma unroll
    for (int t = 0; t < 7; ++t) {
        bf16x8 afx[4];
        if (t < TT) {
            // gather: 16-lane group handles 4 rows in 2 pairs, prefetch-4 + tail
#pragma unroll
            for (int pr = 0; pr < 2; ++pr) {
                int e0[2], cn[2];
#pragma unroll
                for (int i = 0; i < 2; ++i) {
                    int row = qid * 4 + pr * 2 + i;
                    int s = t * 64 + row;
                    int c = bcnt[s];
                    cn[i] = c;
                    e0[i] = bcur[s] - c;   // bcur = segment end after scatter
                }
                int ix[2][4];
#pragma unroll
                for (int i = 0; i < 2; ++i)
#pragma unroll
                    for (int j = 0; j < 4; ++j)
                        ix[i][j] = (cn[i] > j) ? (int)esrt[e0[i] + j] : 0;
                uint4 v[2][4];
#pragma unroll
                for (int i = 0; i < 2; ++i)
#pragma unroll
                    for (int j = 0; j < 4; ++j) {
                        v[i][j] = (uint4){0u, 0u, 0u, 0u};
                        if (cn[i] > j)
                            v[i][j] = *(const uint4*)(xb + (size_t)ix[i][j] * D + l16 * 8);
                    }
#pragma unroll
                for (int i = 0; i < 2; ++i) {
                    float a0 = bflo(v[i][0].x) + bflo(v[i][1].x) + bflo(v[i][2].x) + bflo(v[i][3].x);
                    float a1 = bfhi(v[i][0].x) + bfhi(v[i][1].x) + bfhi(v[i][2].x) + bfhi(v[i][3].x);
                    float a2 = bflo(v[i][0].y) + bflo(v[i][1].y) + bflo(v[i][2].y) + bflo(v[i][3].y);
                    float a3 = bfhi(v[i][0].y) + bfhi(v[i][1].y) + bfhi(v[i][2].y) + bfhi(v[i][3].y);
                    float a4 = bflo(v[i][0].z) + bflo(v[i][1].z) + bflo(v[i][2].z) + bflo(v[i][3].z);
                    float a5 = bfhi(v[i][0].z) + bfhi(v[i][1].z) + bfhi(v[i][2].z) + bfhi(v[i][3].z);
                    float a6 = bflo(v[i][0].w) + bflo(v[i][1].w) + bflo(v[i][2].w) + bflo(v[i][3].w);
                    float a7 = bfhi(v[i][0].w) + bfhi(v[i][1].w) + bfhi(v[i][2].w) + bfhi(v[i][3].w);
                    int e = e0[i] + 4, end = e0[i] + cn[i];
#pragma unroll 1
                    while (e < end) {
                        int s = (int)esrt[e++];
                        uint4 vv = *(const uint4*)(xb + (size_t)s * D + l16 * 8);
                        a0 += bflo(vv.x); a1 += bfhi(vv.x);
                        a2 += bflo(vv.y); a3 += bfhi(vv.y);
                        a4 += bflo(vv.z); a5 += bfhi(vv.z);
                        a6 += bflo(vv.w); a7 += bfhi(vv.w);
                    }
                    if (cn[i] > 1) {
                        float sc = 1.f / (float)cn[i];
                        a0 *= sc; a1 *= sc; a2 *= sc; a3 *= sc;
                        a4 *= sc; a5 *= sc; a6 *= sc; a7 *= sc;
                    }
                    uint4 p;
                    p.x = (unsigned int)f2bf(a0) | ((unsigned int)f2bf(a1) << 16);
                    p.y = (unsigned int)f2bf(a2) | ((unsigned int)f2bf(a3) << 16);
                    p.z = (unsigned int)f2bf(a4) | ((unsigned int)f2bf(a5) << 16);
                    p.w = (unsigned int)f2bf(a6) | ((unsigned int)f2bf(a7) << 16);
                    *(uint4*)&As[lds_off128(qid * 4 + pr * 2 + i, l16)] = p;
                }
            }
        } else {
            // x-slab: A-fragments straight from global xb (no staging)
            int gr = blockRow + wave * 16 + c16; if (gr >= N) gr = N - 1;
#pragma unroll
            for (int ks = 0; ks < 4; ++ks)
                afx[ks] = *(const bf16x8*)(xb + (size_t)gr * D + (ks * 4 + q) * 8);
        }

        // MFMA: K=128 in 4 steps; A from wave-private LDS (or regs), B from L2
        const unsigned short* Bt = Bbase + (size_t)t * 16384;
#pragma unroll
        for (int ks = 0; ks < 4; ++ks) {
            bf16x8 af;
            if (t < TT)
                af = *(const bf16x8*)&As[lds_off128(wave * 16 + c16, ks * 4 + q)];
            else
                af = afx[ks];
#pragma unroll
            for (int ct = 0; ct < 8; ++ct) {
                bf16x8 bfr = *(const bf16x8*)(Bt + ks * 4096 + ct * 128);
                acc[ct] = __builtin_amdgcn_mfma_f32_16x16x32_bf16(af, bfr, acc[ct], 0, 0, 0);
            }
        }
        // no barrier: As rows written and read only by this wave
    }

    // epilogue: bias + LayerNorm + ReLU; nontemporal stores (out never re-read)
    float bias_c[8], g_c[8], bt_c[8];
#pragma unroll
    for (int ct = 0; ct < 8; ++ct) {
        int col = ct * 16 + c16;
        bias_c[ct] = bias_total[col];
        g_c[ct] = gamma[col];
        bt_c[ct] = beta[col];
    }
#pragma unroll
    for (int reg = 0; reg < 4; ++reg) {
        float h[8];
        float s = 0.f, s2 = 0.f;
#pragma unroll
        for (int ct = 0; ct < 8; ++ct) {
            h[ct] = acc[ct][reg] + bias_c[ct];
            s += h[ct];
            s2 += h[ct] * h[ct];
        }
#pragma unroll
        for (int o = 8; o >= 1; o >>= 1) {
            s  += __shfl_xor(s, o, 16);
            s2 += __shfl_xor(s2, o, 16);
        }
        float mu = s * (1.f / 128.f);
        float var = s2 * (1.f / 128.f) - mu * mu;
        float rstd = rsqrtf(var + LN_EPS);
        int row = blockRow + wave * 16 + q * 4 + reg;
        if (row < N) {
#pragma unroll
            for (int ct = 0; ct < 8; ++ct) {
                float y = (h[ct] - mu) * rstd * g_c[ct] + bt_c[ct];
                __builtin_nontemporal_store(fmaxf(y, 0.f),
                    out + (size_t)row * D + ct * 16 + c16);
            }
        }
    }
}

extern "C" void kernel_launch(void* const* d_in, const int* in_sizes, int n_in,
                              void* d_out, int out_size, void* d_ws, size_t ws_size,
                              hipStream_t stream) {
    const float* x     = (const float*)d_in[0];
    const int*   ei    = (const int*)d_in[1];
    const int*   et    = (const int*)d_in[2];
    const float* W_l   = (const float*)d_in[3];
    const float* W_r   = (const float*)d_in[4];
    const float* b     = (const float*)d_in[5];
    const float* emb   = (const float*)d_in[6];
    const float* gamma = (const float*)d_in[7];
    const float* beta  = (const float*)d_in[8];

    int N = in_sizes[0] / D;
    int E = in_sizes[2];
    int NBLK = (N + BM - 1) / BM;      // also the bucket count (dst>>6)

    // workspace carve
    int* bcursor = (int*)d_ws;                            // 8*NBLK*16 (line-padded)
    int* ebuf    = bcursor + 8 * NBLK * 16;               // NBLK * 8*SUBCAP slots
    size_t ofs = (size_t)((char*)(ebuf + (size_t)NBLK * 8 * SUBCAP) - (char*)d_ws);
    ofs = (ofs + 15) & ~(size_t)15;
    unsigned short* WlT = (unsigned short*)((char*)d_ws + ofs);   // 7*16*128*8 ushort
    float* bias_total = (float*)(WlT + 7 * 2048 * 8);             // 128
    size_t ofs2 = (size_t)((char*)(bias_total + D) - (char*)d_ws);
    ofs2 = (ofs2 + 15) & ~(size_t)15;
    unsigned short* xb = (unsigned short*)((char*)d_ws + ofs2);   // N*128 bf16

    hipMemsetAsync(bcursor, 0, (size_t)(8 * NBLK * 16) * sizeof(int), stream);

    int total8 = N * D / 8;
    int G = total8 + 7 * 2048 + D + E;
    prep_kernel<<<(G + 255) / 256, 256, 0, stream>>>(x, W_l, W_r, b, emb, ei, et,
                                                     xb, WlT, bias_total, bcursor, ebuf,
                                                     total8, E, N, NBLK);

    fused_kernel<<<NBLK, 256, 0, stream>>>(xb, bcursor, ebuf, WlT, bias_total,
                                           gamma, beta, (float*)d_out, N);
}